// Round 20
// baseline (66.282 us; speedup 1.0000x reference)
//
#include <hip/hip_runtime.h>
#include <hip/hip_fp8.h>
#include <math.h>

#define L      2048
#define DDIM   512
#define NBATCH 8
#define NTJ    16                         // 128-row j-panels
#define TOTAL_BLOCKS (NBATCH * NTJ * 4)   // 512: (batch, tj, tk-quarter)

#define PANSZ  16384      // bytes per packed 32-row panel (32 rows x 512 k, fp8)

#define ALPHA  0.1f
#define BETA   0.3f
#define MARGIN 2.0f

typedef __attribute__((ext_vector_type(16))) float f32x16;
typedef long long2v __attribute__((ext_vector_type(2)));

#define GLOAD_LDS16(g, l) __builtin_amdgcn_global_load_lds(              \
    (const __attribute__((address_space(1))) unsigned int*)(g),          \
    (__attribute__((address_space(3))) unsigned int*)(l), 16, 0, 0)

// ---------------------------------------------------------------------------
// Kernel 1: fp32 -> fp8 e4m3 PACKED in MFMA-fragment order + exact fp32 sq.
// Packed: [panel=row>>5][kspair=k>>5][fraglane=(row&31)+32*((k>>3)&1)][16B]
// where the 16B holds ksteps (2*kspair, 2*kspair+1) as low/high 8B.
// A lane's fragment for mfma_32x32x16_fp8 (row=l&31, k=(l>>5)*8+e) is then
// ONE contiguous 16B at kspair*1024 + l*16 (low half = even kstep).
// ---------------------------------------------------------------------------
__global__ __launch_bounds__(256) void conv_kernel(const float* __restrict__ pred,
                                                   unsigned char* __restrict__ h,
                                                   float* __restrict__ sq) {
    int w     = threadIdx.x >> 6;
    int lane  = threadIdx.x & 63;
    int batch = blockIdx.x & 7;                 // XCD-aligned with consumer
    int idx   = blockIdx.x >> 3;
    int row   = batch * L + idx * 4 + w;
    const float* p = pred + (size_t)row * DDIM + lane * 8;   // k in [lane*8, +8)
    float4 v0 = *(const float4*)(p);
    float4 v1 = *(const float4*)(p + 4);
    float vals[8] = {v0.x, v0.y, v0.z, v0.w, v1.x, v1.y, v1.z, v1.w};
    unsigned q[8];
    float s = 0.0f;
    #pragma unroll
    for (int i = 0; i < 8; ++i) {
        float x = vals[i];
        s = fmaf(x, x, s);
        __hip_fp8_e4m3 f8(x);
        q[i] = (unsigned)f8.__x;
    }
    unsigned lo = q[0] | (q[1] << 8) | (q[2] << 16) | (q[3] << 24);
    unsigned hi = q[4] | (q[5] << 8) | (q[6] << 16) | (q[7] << 24);
    int r5    = row & 31;
    int pair  = lane >> 2;                 // kstep pair = (lane>>1)>>1
    int khalf = lane & 1;                  // 8-k half within kstep
    int kodd  = (lane >> 1) & 1;           // odd/even kstep of the pair
    size_t off = (size_t)(row >> 5) * PANSZ + pair * 1024
               + (r5 + 32 * khalf) * 16 + kodd * 8;
    *(uint2*)(h + off) = make_uint2(lo, hi);
    #pragma unroll
    for (int o = 32; o > 0; o >>= 1) s += __shfl_down(s, o);
    if (lane == 0) sq[row] = s;
}

// ---------------------------------------------------------------------------
// Kernel 2: A-panel-persistent fp8 Gram GEMM + fused loss. ZERO barriers in
// the main loop. Block = (batch, tj, quarter): stage 4 A row-panels (64KB)
// into LDS once (linear packed copy), one sync, then sweep 4 tk tiles:
// per ks2: 2 ds_read_b128 (A, contiguous = conflict-free) +
// 2 coalesced 1KB global dwordx4 (B, L2-resident) + 8 MFMA. Full matrix,
// weight 1, 512 blocks (perfectly balanced), 2 blocks/CU.
// ---------------------------------------------------------------------------
__global__ __launch_bounds__(256, 2) void loss_kernel(
        const unsigned char* __restrict__ h,
        const int*   __restrict__ seg,
        const float* __restrict__ sq,
        double*      __restrict__ partials) {
    __shared__ unsigned char As[65536];    // 4 row-panels x 16KB

    int bid = blockIdx.x;
    int n   = bid & 7;                     // batch -> XCD
    int r   = bid >> 3;                    // 0..63
    int tj  = r >> 2;                      // 0..15
    int q4  = r & 3;                       // tk quarter

    int t    = threadIdx.x;
    int wid  = t >> 6;                     // 0..3
    int lane = t & 63;
    int wr   = wid >> 1;                   // 0..1 : 64-row half
    int wn   = wid & 1;                    // 0..1 : 64-col half
    int l31  = lane & 31;
    int hsel = lane >> 5;

    const unsigned char* base = h + (size_t)n * L * DDIM;   // batch panels

    // ---- stage A panels (tj*4 .. tj*4+3); wave w copies panel w: 16 KB
    {
        const unsigned char* asrc = base + (size_t)(tj * 4 + wid) * PANSZ + lane * 16;
        unsigned char* adst = As + wid * PANSZ;   // wave-uniform dest
        #pragma unroll
        for (int i = 0; i < 16; ++i)
            GLOAD_LDS16(asrc + i * 1024, adst + i * 1024);
    }
    __syncthreads();   // only barrier in the kernel body

    const int*   segb = seg + n * L;
    const float* sqb  = sq + n * L;

    float lsum = 0.0f;
    int aoff0 = (wr * 2 + 0) * PANSZ + lane * 16;
    int aoff1 = (wr * 2 + 1) * PANSZ + lane * 16;

    #pragma unroll 1
    for (int tkx = 0; tkx < 4; ++tkx) {
        int tk = q4 * 4 + tkx;
        const unsigned char* pb0 = base + (size_t)(tk * 4 + wn * 2) * PANSZ + lane * 16;
        const unsigned char* pb1 = pb0 + PANSZ;

        f32x16 acc[2][2];
        #pragma unroll
        for (int m = 0; m < 2; ++m)
            #pragma unroll
            for (int nf = 0; nf < 2; ++nf)
                #pragma unroll
                for (int x = 0; x < 16; ++x) acc[m][nf][x] = 0.0f;

        #pragma unroll
        for (int ks2 = 0; ks2 < 16; ++ks2) {
            long2v a0 = *(const long2v*)&As[aoff0 + ks2 * 1024];
            long2v a1 = *(const long2v*)&As[aoff1 + ks2 * 1024];
            long2v b0 = *(const long2v*)(pb0 + ks2 * 1024);
            long2v b1 = *(const long2v*)(pb1 + ks2 * 1024);
            acc[0][0] = __builtin_amdgcn_mfma_f32_32x32x16_fp8_fp8(a0.x, b0.x, acc[0][0], 0, 0, 0);
            acc[0][1] = __builtin_amdgcn_mfma_f32_32x32x16_fp8_fp8(a0.x, b1.x, acc[0][1], 0, 0, 0);
            acc[1][0] = __builtin_amdgcn_mfma_f32_32x32x16_fp8_fp8(a1.x, b0.x, acc[1][0], 0, 0, 0);
            acc[1][1] = __builtin_amdgcn_mfma_f32_32x32x16_fp8_fp8(a1.x, b1.x, acc[1][1], 0, 0, 0);
            acc[0][0] = __builtin_amdgcn_mfma_f32_32x32x16_fp8_fp8(a0.y, b0.y, acc[0][0], 0, 0, 0);
            acc[0][1] = __builtin_amdgcn_mfma_f32_32x32x16_fp8_fp8(a0.y, b1.y, acc[0][1], 0, 0, 0);
            acc[1][0] = __builtin_amdgcn_mfma_f32_32x32x16_fp8_fp8(a1.y, b0.y, acc[1][0], 0, 0, 0);
            acc[1][1] = __builtin_amdgcn_mfma_f32_32x32x16_fp8_fp8(a1.y, b1.y, acc[1][1], 0, 0, 0);
        }

        // fused loss for this 128x128 tile (full matrix, weight 1)
        // 32x32 C/D: col = lane&31, row = (reg&3) + 8*(reg>>2) + 4*hsel
        #pragma unroll
        for (int nf = 0; nf < 2; ++nf) {
            int k = tk * 128 + wn * 64 + nf * 32 + l31;
            float sqk = sqb[k];
            int   sgk = segb[k];
            #pragma unroll
            for (int m = 0; m < 2; ++m)
                #pragma unroll
                for (int x = 0; x < 16; ++x) {
                    int j = tj * 128 + wr * 64 + m * 32
                          + (x & 3) + 8 * (x >> 2) + 4 * hsel;
                    float inner = acc[m][nf][x];
                    float d2 = fmaxf(sqb[j] + sqk - 2.0f * inner, 0.0f);
                    float v;
                    if (segb[j] == sgk) {
                        v = ALPHA * d2;
                    } else {
                        float dist = sqrtf(d2);
                        float hg = fmaxf(MARGIN - dist, 0.0f);
                        v = BETA * hg * hg;
                    }
                    lsum += v;
                }
        }
    }

    // per-wave shuffle reduction -> one double per wave (no LDS)
    double dsum = (double)lsum;
    #pragma unroll
    for (int off = 32; off > 0; off >>= 1)
        dsum += __shfl_down(dsum, off);
    if (lane == 0) partials[bid * 4 + wid] = dsum;
}

// ---------------------------------------------------------------------------
// Kernel 3: deterministic final reduction -> mean.
// ---------------------------------------------------------------------------
__global__ __launch_bounds__(256) void reduce_kernel(const double* __restrict__ partials,
                                                     float* __restrict__ out,
                                                     int nPart, double invCount) {
    __shared__ double red[256];
    int t = threadIdx.x;
    double s = 0.0;
    for (int i = t; i < nPart; i += 256) s += partials[i];
    red[t] = s;
    __syncthreads();
    #pragma unroll
    for (int k = 128; k > 0; k >>= 1) {
        if (t < k) red[t] += red[t + k];
        __syncthreads();
    }
    if (t == 0) out[0] = (float)(red[0] * invCount);
}

extern "C" void kernel_launch(void* const* d_in, const int* in_sizes, int n_in,
                              void* d_out, int out_size, void* d_ws, size_t ws_size,
                              hipStream_t stream) {
    const float* pred = (const float*)d_in[0];
    const int*   seg  = (const int*)d_in[1];
    float* out = (float*)d_out;

    const size_t HALF = (size_t)NBATCH * L * DDIM;
    unsigned char* h  = (unsigned char*)d_ws;                // 8.39 MB packed fp8
    float*  sq        = (float*)(h + HALF);                  // 64 KB
    double* partials  = (double*)(sq + NBATCH * L);          // 16 KB

    conv_kernel<<<NBATCH * L / 4, 256, 0, stream>>>(pred, h, sq);
    loss_kernel<<<TOTAL_BLOCKS, 256, 0, stream>>>(h, seg, sq, partials);
    reduce_kernel<<<1, 256, 0, stream>>>(partials, out, TOTAL_BLOCKS * 4,
                                         1.0 / (double)((size_t)NBATCH * L * L));
}

// Round 21
// 55.495 us; speedup vs baseline: 1.1944x; 1.1944x over previous
//
#include <hip/hip_runtime.h>
#include <hip/hip_fp8.h>
#include <math.h>

#define L      2048
#define DDIM   512
#define NBATCH 8
#define BM     128
#define BN     128
#define NTILE  (L / BM)                  // 16
#define NPAIR  (NTILE * (NTILE + 1) / 2) // 136
#define TOTAL_BLOCKS (NBATCH * NPAIR)    // 1088

#define PANSZ  16384     // bytes per packed 32-row fp8 panel (32 rows x 512 k)

#define ALPHA  0.1f
#define BETA   0.3f
#define MARGIN 2.0f

typedef __attribute__((ext_vector_type(16))) float f32x16;
typedef long long2v __attribute__((ext_vector_type(2)));

// ---------------------------------------------------------------------------
// Kernel 1: fp32 -> fp8 e4m3 PACKED in MFMA-fragment order + exact fp32 sq.
// (verified R20: absmax == 0.0)  Packed: [panel=row>>5][kspair=k>>5]
// [fraglane=(row&31)+32*((k>>3)&1)][16B]; 16B = ksteps (2p, 2p+1) lo/hi 8B.
// ---------------------------------------------------------------------------
__global__ __launch_bounds__(256) void conv_kernel(const float* __restrict__ pred,
                                                   unsigned char* __restrict__ h,
                                                   float* __restrict__ sq) {
    int w     = threadIdx.x >> 6;
    int lane  = threadIdx.x & 63;
    int batch = blockIdx.x & 7;
    int idx   = blockIdx.x >> 3;
    int row   = batch * L + idx * 4 + w;
    const float* p = pred + (size_t)row * DDIM + lane * 8;
    float4 v0 = *(const float4*)(p);
    float4 v1 = *(const float4*)(p + 4);
    float vals[8] = {v0.x, v0.y, v0.z, v0.w, v1.x, v1.y, v1.z, v1.w};
    unsigned q[8];
    float s = 0.0f;
    #pragma unroll
    for (int i = 0; i < 8; ++i) {
        float x = vals[i];
        s = fmaf(x, x, s);
        __hip_fp8_e4m3 f8(x);
        q[i] = (unsigned)f8.__x;
    }
    unsigned lo = q[0] | (q[1] << 8) | (q[2] << 16) | (q[3] << 24);
    unsigned hi = q[4] | (q[5] << 8) | (q[6] << 16) | (q[7] << 24);
    int r5    = row & 31;
    int pair  = lane >> 2;
    int khalf = lane & 1;
    int kodd  = (lane >> 1) & 1;
    size_t off = (size_t)(row >> 5) * PANSZ + pair * 1024
               + (r5 + 32 * khalf) * 16 + kodd * 8;
    *(uint2*)(h + off) = make_uint2(lo, hi);
    #pragma unroll
    for (int o = 32; o > 0; o >>= 1) s += __shfl_down(s, o);
    if (lane == 0) sq[row] = s;
}

// ---------------------------------------------------------------------------
// Kernel 2: register-direct fp8 Gram GEMM, DEPTH-3 software prefetch,
// NO LDS / NO barriers. 128x128 tile, 4 waves (2x2 of 64x64, 2x2 frags of
// 32x32), mfma_f32_32x32x16_fp8_fp8. 16 kspair iterations fully unrolled:
// iteration p: 8 MFMA on data loaded at p-3, then issue 4 coalesced 1KB
// loads for p+3 (~768 cyc of cover >> L2 latency). Compiler inserts counted
// vmcnt automatically. Symmetric grid (tj<=tk), weights {2,1,0}.
// ---------------------------------------------------------------------------
__global__ __launch_bounds__(256) void loss_kernel(
        const unsigned char* __restrict__ h,
        const int*   __restrict__ seg,
        const float* __restrict__ sq,
        double*      __restrict__ partials) {
    __shared__ double wred[4];

    int bid = blockIdx.x;
    int n = bid & 7;            // batch -> XCD (L2-resident: 1 MB fp8/batch)
    int p = bid >> 3;           // 0..135
    int tj = 0;
    while (true) {
        int rl2 = NTILE - tj;
        if (p < rl2) break;
        p -= rl2;
        ++tj;
    }
    int tk = tj + p;

    int t    = threadIdx.x;
    int wid  = t >> 6;          // 0..3
    int lane = t & 63;
    int wr   = wid >> 1, wc = wid & 1;   // 64x64 quadrant
    int l31  = lane & 31;
    int hsel = lane >> 5;

    const unsigned char* base = h + (size_t)n * L * DDIM;

    // fragment base pointers (panel idx: A = tj*4 + wr*2 + m, B = tk*4 + wc*2 + nf)
    const unsigned char* pa0 = base + (size_t)(tj * 4 + wr * 2 + 0) * PANSZ + lane * 16;
    const unsigned char* pa1 = base + (size_t)(tj * 4 + wr * 2 + 1) * PANSZ + lane * 16;
    const unsigned char* pb0 = base + (size_t)(tk * 4 + wc * 2 + 0) * PANSZ + lane * 16;
    const unsigned char* pb1 = base + (size_t)(tk * 4 + wc * 2 + 1) * PANSZ + lane * 16;

    f32x16 acc[2][2];
    #pragma unroll
    for (int m = 0; m < 2; ++m)
        #pragma unroll
        for (int nf = 0; nf < 2; ++nf)
            #pragma unroll
            for (int x = 0; x < 16; ++x) acc[m][nf][x] = 0.0f;

    // depth-3 rotating prefetch slots (compile-time indices under full unroll)
    long2v ra0[3], ra1[3], rb0[3], rb1[3];
    #pragma unroll
    for (int q = 0; q < 3; ++q) {
        ra0[q] = *(const long2v*)(pa0 + q * 1024);
        ra1[q] = *(const long2v*)(pa1 + q * 1024);
        rb0[q] = *(const long2v*)(pb0 + q * 1024);
        rb1[q] = *(const long2v*)(pb1 + q * 1024);
    }

    #pragma unroll
    for (int ks2 = 0; ks2 < 16; ++ks2) {
        const int slot = ks2 % 3;               // compile-time
        long2v a0 = ra0[slot], a1 = ra1[slot];
        long2v b0 = rb0[slot], b1 = rb1[slot];

        acc[0][0] = __builtin_amdgcn_mfma_f32_32x32x16_fp8_fp8(a0.x, b0.x, acc[0][0], 0, 0, 0);
        acc[0][1] = __builtin_amdgcn_mfma_f32_32x32x16_fp8_fp8(a0.x, b1.x, acc[0][1], 0, 0, 0);
        acc[1][0] = __builtin_amdgcn_mfma_f32_32x32x16_fp8_fp8(a1.x, b0.x, acc[1][0], 0, 0, 0);
        acc[1][1] = __builtin_amdgcn_mfma_f32_32x32x16_fp8_fp8(a1.x, b1.x, acc[1][1], 0, 0, 0);
        acc[0][0] = __builtin_amdgcn_mfma_f32_32x32x16_fp8_fp8(a0.y, b0.y, acc[0][0], 0, 0, 0);
        acc[0][1] = __builtin_amdgcn_mfma_f32_32x32x16_fp8_fp8(a0.y, b1.y, acc[0][1], 0, 0, 0);
        acc[1][0] = __builtin_amdgcn_mfma_f32_32x32x16_fp8_fp8(a1.y, b0.y, acc[1][0], 0, 0, 0);
        acc[1][1] = __builtin_amdgcn_mfma_f32_32x32x16_fp8_fp8(a1.y, b1.y, acc[1][1], 0, 0, 0);

        if (ks2 + 3 < 16) {
            ra0[slot] = *(const long2v*)(pa0 + (ks2 + 3) * 1024);
            ra1[slot] = *(const long2v*)(pa1 + (ks2 + 3) * 1024);
            rb0[slot] = *(const long2v*)(pb0 + (ks2 + 3) * 1024);
            rb1[slot] = *(const long2v*)(pb1 + (ks2 + 3) * 1024);
        }
    }

    // ------------------- fused loss epilogue -------------------
    // 32x32 C/D layout: col = lane&31, row = (reg&3) + 8*(reg>>2) + 4*hsel
    const int*   segb = seg + n * L;
    const float* sqb  = sq + n * L;
    int j0 = tj * BM, k0 = tk * BN;

    float lsum = 0.0f;    // weighted: skip j>k, 2x j<k, 1x j==k
    #pragma unroll
    for (int nf = 0; nf < 2; ++nf) {
        int k = k0 + wc * 64 + nf * 32 + l31;
        float sqk = sqb[k];
        int   sgk = segb[k];
        #pragma unroll
        for (int m = 0; m < 2; ++m)
            #pragma unroll
            for (int x = 0; x < 16; ++x) {
                int j = j0 + wr * 64 + m * 32 + (x & 3) + 8 * (x >> 2) + 4 * hsel;
                if (j > k) continue;
                float inner = acc[m][nf][x];
                float d2 = fmaxf(sqb[j] + sqk - 2.0f * inner, 0.0f);
                float v;
                if (segb[j] == sgk) {
                    v = ALPHA * d2;
                } else {
                    float dist = sqrtf(d2);
                    float hg = fmaxf(MARGIN - dist, 0.0f);
                    v = BETA * hg * hg;
                }
                lsum += (j < k) ? 2.0f * v : v;
            }
    }

    double wgt = 1.0;   // weights already per-element
    double dsum = (double)lsum * wgt;
    #pragma unroll
    for (int off = 32; off > 0; off >>= 1)
        dsum += __shfl_down(dsum, off);
    if (lane == 0) wred[wid] = dsum;
    __syncthreads();
    if (t == 0) partials[bid] = (wred[0] + wred[1]) + (wred[2] + wred[3]);
}

// ---------------------------------------------------------------------------
// Kernel 3: deterministic final reduction -> mean.
// ---------------------------------------------------------------------------
__global__ __launch_bounds__(256) void reduce_kernel(const double* __restrict__ partials,
                                                     float* __restrict__ out,
                                                     int nPart, double invCount) {
    __shared__ double red[256];
    int t = threadIdx.x;
    double s = 0.0;
    for (int i = t; i < nPart; i += 256) s += partials[i];
    red[t] = s;
    __syncthreads();
    #pragma unroll
    for (int k = 128; k > 0; k >>= 1) {
        if (t < k) red[t] += red[t + k];
        __syncthreads();
    }
    if (t == 0) out[0] = (float)(red[0] * invCount);
}

extern "C" void kernel_launch(void* const* d_in, const int* in_sizes, int n_in,
                              void* d_out, int out_size, void* d_ws, size_t ws_size,
                              hipStream_t stream) {
    const float* pred = (const float*)d_in[0];
    const int*   seg  = (const int*)d_in[1];
    float* out = (float*)d_out;

    const size_t HALF = (size_t)NBATCH * L * DDIM;
    unsigned char* h  = (unsigned char*)d_ws;                // 8.39 MB packed fp8
    float*  sq        = (float*)(h + HALF);                  // 64 KB
    double* partials  = (double*)(sq + NBATCH * L);          // 8.7 KB

    conv_kernel<<<NBATCH * L / 4, 256, 0, stream>>>(pred, h, sq);
    loss_kernel<<<TOTAL_BLOCKS, 256, 0, stream>>>(h, seg, sq, partials);
    reduce_kernel<<<1, 256, 0, stream>>>(partials, out, TOTAL_BLOCKS,
                                         1.0 / (double)((size_t)NBATCH * L * L));
}